// Round 6
// baseline (513.066 us; speedup 1.0000x reference)
//
#include <hip/hip_runtime.h>
#include <stdint.h>

typedef __attribute__((ext_vector_type(4))) float  float4v;
typedef __attribute__((ext_vector_type(8))) __bf16 bf16x8;
typedef __attribute__((ext_vector_type(8))) unsigned short ushort8;

#define B_DIM 8192
#define H_DIM 1024
#define O_DIM 1024

static __device__ __forceinline__ unsigned short f32_to_bf16(float f) {
  union { float f; unsigned int u; } v; v.f = f;
  unsigned int u = v.u;
  unsigned int r = u + 0x7FFFu + ((u >> 16) & 1u);  // round-to-nearest-even
  return (unsigned short)(r >> 16);
}

// ---------------------------------------------------------------------------
// prep_inputs: unchanged (near memory floor).
// ---------------------------------------------------------------------------
__global__ void prep_inputs(const float* __restrict__ state,
                            const float* __restrict__ basis,
                            const float* __restrict__ prjw,
                            unsigned short* __restrict__ Abf,
                            unsigned short* __restrict__ Wt) {
  __shared__ __align__(16) unsigned short t[64 * 72];
  int bb = blockIdx.x;
  int tid = threadIdx.x;
  if (bb < 1280) {
    int m = bb >> 8, panel = bb & 255;
    int o0 = (panel & 15) * 64, h0 = (panel >> 4) * 64;
    const float* src = (m < 4) ? (basis + (size_t)m * H_DIM * O_DIM) : prjw;  // [H][O]
    int r  = tid >> 4;
    int c4 = (tid & 15) * 4;
#pragma unroll
    for (int p = 0; p < 4; ++p) {
      int h = r + p * 16;
      float4v v = *(const float4v*)(src + (size_t)(h0 + h) * O_DIM + o0 + c4);
      t[(c4 + 0) * 72 + h] = f32_to_bf16(v.x);
      t[(c4 + 1) * 72 + h] = f32_to_bf16(v.y);
      t[(c4 + 2) * 72 + h] = f32_to_bf16(v.z);
      t[(c4 + 3) * 72 + h] = f32_to_bf16(v.w);
    }
    __syncthreads();
#pragma unroll
    for (int i = 0; i < 2; ++i) {
      int C = i * 256 + tid;
      int o = C >> 3, cc = C & 7;
      ushort8 val = *(const ushort8*)(t + o * 72 + cc * 8);
      *(ushort8*)(Wt + ((size_t)m * O_DIM + o0 + o) * H_DIM + h0 + cc * 8) = val;
    }
  } else {
    int i = (bb - 1280) * 256 + tid;  // 8 elems per thread
    float4v v0 = ((const float4v*)state)[i * 2];
    float4v v1 = ((const float4v*)state)[i * 2 + 1];
    ushort8 o;
    o[0] = f32_to_bf16(v0.x); o[1] = f32_to_bf16(v0.y);
    o[2] = f32_to_bf16(v0.z); o[3] = f32_to_bf16(v0.w);
    o[4] = f32_to_bf16(v1.x); o[5] = f32_to_bf16(v1.y);
    o[6] = f32_to_bf16(v1.z); o[7] = f32_to_bf16(v1.w);
    ((ushort8*)Abf)[i] = o;
  }
}

// ---------------------------------------------------------------------------
// R5: register-direct K-loop — NO LDS staging, NO barriers in the main loop.
//  R1-R4 were bounded ~42% MfmaUtil by the LDS round trip: per CU-stage,
//  ~112KB ds_read + 57KB lds-write (~1300cyc at 85B/cyc) serialized against
//  1288cyc of matrix work, plus 8-wave barrier skew.  Both operands are
//  64B-aligned full-cacheline row segments, so direct global loads fetch the
//  SAME L2 lines with zero LDS traffic.  Each wave streams independently:
//  double-buffered fragment sets (E/O), 1-stage lookahead, compiler-counted
//  vmcnt (never a drain), setprio around MFMA clusters.
//  Tile 128x64, 4 waves, wave-tile 64x32 (unchanged math & operand mapping:
//  lane(q,ln) reads A[row][8q..8q+8) — identical bytes to the old swizzled
//  LDS path, so layout correctness is inherited).  LDS now epilogue-only.
// ---------------------------------------------------------------------------
__global__ __launch_bounds__(256, 2)
void gemm_fused(const unsigned short* __restrict__ A,
                const unsigned short* __restrict__ Wt,
                const float* __restrict__ se, const float* __restrict__ curv,
                const float* __restrict__ gw, const float* __restrict__ gb,
                const float* __restrict__ prjb,
                float* __restrict__ out) {
  __shared__ __align__(16) unsigned char smem[39424];
  float* scf = (float*)(smem + 36864);  // 5 x 128 fp32

  const int tid  = threadIdx.x;
  const int lane = tid & 63;
  const int wave = tid >> 6;
  const int row0 = blockIdx.x * 128;
  const int col0 = blockIdx.y * 64;
  const int wrow = (wave >> 1) * 64;   // 0 or 64
  const int wcol = (wave & 1) * 32;    // 0 or 32
  const int q  = lane >> 4;
  const int ln = lane & 15;

  // ---- fused coeff prep: coeff[m][row] for this block's 128 rows
  if (tid < 128) {
    int b = row0 + tid;
    float s = se[b];
    float l0 = fmaf(s, gw[0], gb[0]);
    float l1 = fmaf(s, gw[1], gb[1]);
    float l2 = fmaf(s, gw[2], gb[2]);
    float l3 = fmaf(s, gw[3], gb[3]);
    float mx = fmaxf(fmaxf(l0, l1), fmaxf(l2, l3));
    float e0 = __expf(l0 - mx), e1 = __expf(l1 - mx);
    float e2 = __expf(l2 - mx), e3 = __expf(l3 - mx);
    float mix = 1.0f / (1.0f + __expf(-curv[b]));
    float inv = mix / (e0 + e1 + e2 + e3);
    scf[0 * 128 + tid] = e0 * inv;
    scf[1 * 128 + tid] = e1 * inv;
    scf[2 * 128 + tid] = e2 * inv;
    scf[3 * 128 + tid] = e3 * inv;
    scf[4 * 128 + tid] = 1.0f - mix;
  }

  // ---- per-lane operand pointers (64B row segments; lane reads 16B at 8q)
  const unsigned short* pA[4];
#pragma unroll
  for (int t = 0; t < 4; ++t)
    pA[t] = A + (size_t)(row0 + wrow + 16 * t + ln) * H_DIM + 8 * q;
  const unsigned short* pB[5][2];
#pragma unroll
  for (int m = 0; m < 5; ++m)
#pragma unroll
    for (int j = 0; j < 2; ++j)
      pB[m][j] = Wt + (size_t)m * O_DIM * H_DIM +
                 (size_t)(col0 + wcol + 16 * j + ln) * H_DIM + 8 * q;

  float4v acc[5][4][2];
#pragma unroll
  for (int m = 0; m < 5; ++m)
#pragma unroll
    for (int i = 0; i < 4; ++i)
#pragma unroll
      for (int j = 0; j < 2; ++j)
        acc[m][i][j] = (float4v){0.f, 0.f, 0.f, 0.f};

  // fragment sets: E (even stage) / O (odd stage), double-buffered
  bf16x8 ae[4], beF[5][2], ao[4], boF[5][2];

#define LOADSET(aF, bF, koff)                                                   \
  do {                                                                          \
    _Pragma("unroll")                                                           \
    for (int _t = 0; _t < 4; ++_t)                                              \
      aF[_t] = *(const bf16x8*)(pA[_t] + (koff));                               \
    _Pragma("unroll")                                                           \
    for (int _m = 0; _m < 5; ++_m) {                                            \
      bF[_m][0] = *(const bf16x8*)(pB[_m][0] + (koff));                         \
      bF[_m][1] = *(const bf16x8*)(pB[_m][1] + (koff));                         \
    }                                                                           \
  } while (0)

#define MFMASET(aF, bF)                                                         \
  do {                                                                          \
    __builtin_amdgcn_s_setprio(1);                                              \
    _Pragma("unroll")                                                           \
    for (int _m = 0; _m < 5; ++_m)                                              \
      _Pragma("unroll")                                                         \
      for (int _t = 0; _t < 4; ++_t) {                                          \
        acc[_m][_t][0] = __builtin_amdgcn_mfma_f32_16x16x32_bf16(               \
            aF[_t], bF[_m][0], acc[_m][_t][0], 0, 0, 0);                        \
        acc[_m][_t][1] = __builtin_amdgcn_mfma_f32_16x16x32_bf16(               \
            aF[_t], bF[_m][1], acc[_m][_t][1], 0, 0, 0);                        \
      }                                                                         \
    __builtin_amdgcn_s_setprio(0);                                              \
  } while (0)

#define BUMP64                                                                  \
  do {                                                                          \
    _Pragma("unroll") for (int _t = 0; _t < 4; ++_t) pA[_t] += 64;              \
    _Pragma("unroll") for (int _m = 0; _m < 5; ++_m) {                          \
      pB[_m][0] += 64; pB[_m][1] += 64;                                         \
    }                                                                           \
  } while (0)

  LOADSET(ae, beF, 0);          // stage 0 in flight; scf prep covered latency
  for (int it = 0; it < 15; ++it) {
    LOADSET(ao, boF, 32);       // stage 2it+1 (issue before computing 2it)
    MFMASET(ae, beF);           // stage 2it  (compiler: counted vmcnt wait)
    LOADSET(ae, beF, 64);       // stage 2it+2
    MFMASET(ao, boF);           // stage 2it+1
    BUMP64;
  }
  LOADSET(ao, boF, 32);         // stage 31
  MFMASET(ae, beF);             // stage 30
  MFMASET(ao, boF);             // stage 31

  // ---- epilogue: mode-combine -> LDS repack (fp32, pitch 68) -> float4 stores
  __syncthreads();             // scf visible; all waves ready for fbuf reuse
  float* fbuf = (float*)smem;  // 128 x 68 fp32 = 34816 B (scf at 36864 safe)
#pragma unroll
  for (int ti = 0; ti < 4; ++ti) {
    int rl = wrow + ti * 16 + q * 4;
#pragma unroll
    for (int tj = 0; tj < 2; ++tj) {
      int cc = wcol + tj * 16 + ln;
#pragma unroll
      for (int r = 0; r < 4; ++r) {
        float v = 0.f;
#pragma unroll
        for (int m = 0; m < 5; ++m)
          v += scf[m * 128 + rl + r] * acc[m][ti][tj][r];
        fbuf[(rl + r) * 68 + cc] = v;
      }
    }
  }
  __syncthreads();
#pragma unroll
  for (int i = 0; i < 8; ++i) {
    int L = i * 256 + tid;          // 2048 float4s = 128 rows x 16
    int row = L >> 4, c4 = L & 15;
    float4v v = *(const float4v*)(fbuf + row * 68 + c4 * 4);
    float cb = scf[4 * 128 + row];
    float4v pb = *(const float4v*)(prjb + col0 + c4 * 4);
    v += cb * pb;
    *(float4v*)(out + (size_t)(row0 + row) * O_DIM + col0 + c4 * 4) = v;
  }
#undef LOADSET
#undef MFMASET
#undef BUMP64
}

// ---------------------------------------------------------------------------
extern "C" void kernel_launch(void* const* d_in, const int* in_sizes, int n_in,
                              void* d_out, int out_size, void* d_ws, size_t ws_size,
                              hipStream_t stream) {
  const float* state = (const float*)d_in[0];
  const float* se    = (const float*)d_in[1];
  const float* curv  = (const float*)d_in[2];
  const float* basis = (const float*)d_in[3];
  const float* gw    = (const float*)d_in[4];
  const float* gb    = (const float*)d_in[5];
  const float* prjw  = (const float*)d_in[6];
  const float* prjb  = (const float*)d_in[7];
  float* out = (float*)d_out;

  char* ws = (char*)d_ws;
  unsigned short* Abf = (unsigned short*)ws;                               // 16 MB
  unsigned short* Wt  = (unsigned short*)(ws + (size_t)16 * 1024 * 1024);  // 10 MB

  prep_inputs<<<5376, 256, 0, stream>>>(state, basis, prjw, Abf, Wt);
  dim3 gg(B_DIM / 128, O_DIM / 64);
  gemm_fused<<<gg, 256, 0, stream>>>(Abf, Wt, se, curv, gw, gb, prjb, out);
}

// Round 9
// 182.968 us; speedup vs baseline: 2.8041x; 2.8041x over previous
//
#include <hip/hip_runtime.h>
#include <stdint.h>

typedef __attribute__((ext_vector_type(4))) float  float4v;
typedef __attribute__((ext_vector_type(8))) __bf16 bf16x8;
typedef __attribute__((ext_vector_type(8))) unsigned short ushort8;

#define B_DIM 8192
#define H_DIM 1024
#define O_DIM 1024

static __device__ __forceinline__ unsigned short f32_to_bf16(float f) {
  union { float f; unsigned int u; } v; v.f = f;
  unsigned int u = v.u;
  unsigned int r = u + 0x7FFFu + ((u >> 16) & 1u);  // round-to-nearest-even
  return (unsigned short)(r >> 16);
}

// ---------------------------------------------------------------------------
// prep_inputs: unchanged (near memory floor).
// ---------------------------------------------------------------------------
__global__ void prep_inputs(const float* __restrict__ state,
                            const float* __restrict__ basis,
                            const float* __restrict__ prjw,
                            unsigned short* __restrict__ Abf,
                            unsigned short* __restrict__ Wt) {
  __shared__ __align__(16) unsigned short t[64 * 72];
  int bb = blockIdx.x;
  int tid = threadIdx.x;
  if (bb < 1280) {
    int m = bb >> 8, panel = bb & 255;
    int o0 = (panel & 15) * 64, h0 = (panel >> 4) * 64;
    const float* src = (m < 4) ? (basis + (size_t)m * H_DIM * O_DIM) : prjw;  // [H][O]
    int r  = tid >> 4;
    int c4 = (tid & 15) * 4;
#pragma unroll
    for (int p = 0; p < 4; ++p) {
      int h = r + p * 16;
      float4v v = *(const float4v*)(src + (size_t)(h0 + h) * O_DIM + o0 + c4);
      t[(c4 + 0) * 72 + h] = f32_to_bf16(v.x);
      t[(c4 + 1) * 72 + h] = f32_to_bf16(v.y);
      t[(c4 + 2) * 72 + h] = f32_to_bf16(v.z);
      t[(c4 + 3) * 72 + h] = f32_to_bf16(v.w);
    }
    __syncthreads();
#pragma unroll
    for (int i = 0; i < 2; ++i) {
      int C = i * 256 + tid;
      int o = C >> 3, cc = C & 7;
      ushort8 val = *(const ushort8*)(t + o * 72 + cc * 8);
      *(ushort8*)(Wt + ((size_t)m * O_DIM + o0 + o) * H_DIM + h0 + cc * 8) = val;
    }
  } else {
    int i = (bb - 1280) * 256 + tid;  // 8 elems per thread
    float4v v0 = ((const float4v*)state)[i * 2];
    float4v v1 = ((const float4v*)state)[i * 2 + 1];
    ushort8 o;
    o[0] = f32_to_bf16(v0.x); o[1] = f32_to_bf16(v0.y);
    o[2] = f32_to_bf16(v0.z); o[3] = f32_to_bf16(v0.w);
    o[4] = f32_to_bf16(v1.x); o[5] = f32_to_bf16(v1.y);
    o[6] = f32_to_bf16(v1.z); o[7] = f32_to_bf16(v1.w);
    ((ushort8*)Abf)[i] = o;
  }
}

// ---------------------------------------------------------------------------
// R8 = R7 with the LDS allocation fixed: smem 113152 -> 115712.
//  R7's absmax 34.8 was an OOB scf: the scf array (5 x 256 fp32 = 5120 B at
//  offset 110592) only had 2560 B allocated; modes 2-4 and the base coeff
//  were dropped/zero on OOB ds ops.  (R6's 58.8 = this + the B-offset bug.)
//  Structure (unchanged): counted-vmcnt 3-ring + intra-stage interleave.
//  Tile 256(B) x 64(O); 512 thr = 8 waves; BK=32, 32 stages; 3 x 36KB ring.
//  Per stage: ONE s_barrier + ONE counted vmcnt(L) (L=4 A-duty / 5 B-duty).
//  Body: ISSUE s+2 -> ph1 ds_reads(slot s) -> MFMA ph0(carried)+ph1 ->
//  vmcnt(L) -> s_barrier -> sched_barrier(0) -> READ_PH0(slot s+1).
// ---------------------------------------------------------------------------
__global__ __launch_bounds__(512, 2)
void gemm_fused(const unsigned short* __restrict__ A,
                const unsigned short* __restrict__ Wt,
                const float* __restrict__ se, const float* __restrict__ curv,
                const float* __restrict__ gw, const float* __restrict__ gb,
                const float* __restrict__ prjb,
                float* __restrict__ out) {
  __shared__ __align__(16) unsigned char smem[115712];  // 3*36864 + 5120 (scf)
  float* scf = (float*)(smem + 110592);  // 5 x 256 fp32 = 5120 B

  const int tid  = threadIdx.x;
  const int lane = tid & 63;
  const int wave = tid >> 6;
  const int row0 = blockIdx.x * 256;
  const int col0 = blockIdx.y * 64;
  const int wrow = (wave >> 1) * 64;   // 0,64,128,192
  const int wcol = (wave & 1) * 32;    // 0 or 32
  const int q  = lane >> 4;
  const int ln = lane & 15;

  // ---- staging descriptors.  1KB wave-chunk = 16 rows x 32k bf16.
  const unsigned short* gsrc[5];
  unsigned int ldsoff[5];
  if (wave < 4) {
#pragma unroll
    for (int j = 0; j < 4; ++j) {
      int c = wave * 4 + j;                 // A chunk 0..15
      int row = c * 16 + (lane >> 2);
      int pos = lane & 3;
      int g = pos ^ ((row >> 1) & 3);
      gsrc[j] = A + (size_t)(row0 + row) * H_DIM + g * 8;
      ldsoff[j] = c * 1024;
    }
    gsrc[4] = gsrc[0]; ldsoff[4] = ldsoff[0];  // never issued for A-waves
  } else {
#pragma unroll
    for (int j = 0; j < 5; ++j) {
      int c = (wave - 4) * 5 + j;           // B chunk 0..19
      int m = c >> 2;                       // mode (4 chunks per mode)
      int r = (c & 3) * 16 + (lane >> 2);   // row within mode slab (0..63)
      int pos = lane & 3;
      int g = pos ^ ((r >> 1) & 3);
      gsrc[j] = Wt + (size_t)m * O_DIM * H_DIM + (size_t)(col0 + r) * H_DIM + g * 8;
      ldsoff[j] = 16384 + c * 1024;
    }
  }

  // ---- loop-invariant fragment byte offsets (ushort units; row = 32 ushorts)
  int aoffs[4];
#pragma unroll
  for (int t = 0; t < 4; ++t) {
    int ra = wrow + t * 16 + ln;
    aoffs[t] = ra * 32 + (q ^ ((ra >> 1) & 3)) * 8;
  }
  int boffs[2];
  {
    int rb = wcol + ln;      boffs[0] = rb * 32 + (q ^ ((rb >> 1) & 3)) * 8;
    int r1 = wcol + 16 + ln; boffs[1] = r1 * 32 + (q ^ ((r1 >> 1) & 3)) * 8;
  }

  float4v acc[5][4][2];
#pragma unroll
  for (int m = 0; m < 5; ++m)
#pragma unroll
    for (int i = 0; i < 4; ++i)
#pragma unroll
      for (int j = 0; j < 2; ++j)
        acc[m][i][j] = (float4v){0.f, 0.f, 0.f, 0.f};

#define ISSUE_SLOT(boff_)                                                       \
  do {                                                                          \
    unsigned char* _dst = smem + (boff_);                                       \
    __builtin_amdgcn_global_load_lds(                                           \
        (const __attribute__((address_space(1))) void*)gsrc[0],                 \
        (__attribute__((address_space(3))) void*)(_dst + ldsoff[0]), 16, 0, 0); \
    __builtin_amdgcn_global_load_lds(                                           \
        (const __attribute__((address_space(1))) void*)gsrc[1],                 \
        (__attribute__((address_space(3))) void*)(_dst + ldsoff[1]), 16, 0, 0); \
    __builtin_amdgcn_global_load_lds(                                           \
        (const __attribute__((address_space(1))) void*)gsrc[2],                 \
        (__attribute__((address_space(3))) void*)(_dst + ldsoff[2]), 16, 0, 0); \
    __builtin_amdgcn_global_load_lds(                                           \
        (const __attribute__((address_space(1))) void*)gsrc[3],                 \
        (__attribute__((address_space(3))) void*)(_dst + ldsoff[3]), 16, 0, 0); \
    if (wave >= 4)                                                              \
      __builtin_amdgcn_global_load_lds(                                         \
          (const __attribute__((address_space(1))) void*)gsrc[4],               \
          (__attribute__((address_space(3))) void*)(_dst + ldsoff[4]), 16, 0, 0);\
    _Pragma("unroll") for (int _j = 0; _j < 5; ++_j) gsrc[_j] += 32;            \
  } while (0)

#define WAITL                                                                   \
  do { if (wave < 4) asm volatile("s_waitcnt vmcnt(4)" ::: "memory");           \
       else          asm volatile("s_waitcnt vmcnt(5)" ::: "memory"); } while (0)

  // persistent ph0 fragments (carried across the barrier)
  bf16x8 a0, a1, a2, a3, b00, b01, b10, b11;

#define READ_PH0(boff_)                                                         \
  do {                                                                          \
    const unsigned short* _sA = (const unsigned short*)(smem + (boff_));        \
    const unsigned short* _sB = _sA + 8192;                                     \
    a0 = *(const bf16x8*)(_sA + aoffs[0]);                                      \
    a1 = *(const bf16x8*)(_sA + aoffs[1]);                                      \
    a2 = *(const bf16x8*)(_sA + aoffs[2]);                                      \
    a3 = *(const bf16x8*)(_sA + aoffs[3]);                                      \
    b00 = *(const bf16x8*)(_sB + boffs[0]);                                     \
    b01 = *(const bf16x8*)(_sB + boffs[1]);                                     \
    b10 = *(const bf16x8*)(_sB + 2048 + boffs[0]);                              \
    b11 = *(const bf16x8*)(_sB + 2048 + boffs[1]);                              \
  } while (0)

#define MFMA_MODE(m_, bb0, bb1)                                                 \
  do {                                                                          \
    acc[m_][0][0] = __builtin_amdgcn_mfma_f32_16x16x32_bf16(a0, bb0, acc[m_][0][0], 0, 0, 0); \
    acc[m_][1][0] = __builtin_amdgcn_mfma_f32_16x16x32_bf16(a1, bb0, acc[m_][1][0], 0, 0, 0); \
    acc[m_][2][0] = __builtin_amdgcn_mfma_f32_16x16x32_bf16(a2, bb0, acc[m_][2][0], 0, 0, 0); \
    acc[m_][3][0] = __builtin_amdgcn_mfma_f32_16x16x32_bf16(a3, bb0, acc[m_][3][0], 0, 0, 0); \
    acc[m_][0][1] = __builtin_amdgcn_mfma_f32_16x16x32_bf16(a0, bb1, acc[m_][0][1], 0, 0, 0); \
    acc[m_][1][1] = __builtin_amdgcn_mfma_f32_16x16x32_bf16(a1, bb1, acc[m_][1][1], 0, 0, 0); \
    acc[m_][2][1] = __builtin_amdgcn_mfma_f32_16x16x32_bf16(a2, bb1, acc[m_][2][1], 0, 0, 0); \
    acc[m_][3][1] = __builtin_amdgcn_mfma_f32_16x16x32_bf16(a3, bb1, acc[m_][3][1], 0, 0, 0); \
  } while (0)

// B region of a slot = ushort offset 8192 (byte 16384).  Mode m at +m*2048.
#define PH1_READS(boff_)                                                        \
  const unsigned short* _cB = (const unsigned short*)(smem + (boff_)) + 8192;   \
  bf16x8 c20 = *(const bf16x8*)(_cB + 2 * 2048 + boffs[0]);                     \
  bf16x8 c21 = *(const bf16x8*)(_cB + 2 * 2048 + boffs[1]);                     \
  bf16x8 c30 = *(const bf16x8*)(_cB + 3 * 2048 + boffs[0]);                     \
  bf16x8 c31 = *(const bf16x8*)(_cB + 3 * 2048 + boffs[1]);                     \
  bf16x8 c40 = *(const bf16x8*)(_cB + 4 * 2048 + boffs[0]);                     \
  bf16x8 c41 = *(const bf16x8*)(_cB + 4 * 2048 + boffs[1])

#define MFMA_ALL5                                                               \
  do {                                                                          \
    __builtin_amdgcn_s_setprio(1);                                              \
    MFMA_MODE(0, b00, b01);                                                     \
    MFMA_MODE(1, b10, b11);                                                     \
    MFMA_MODE(2, c20, c21);                                                     \
    MFMA_MODE(3, c30, c31);                                                     \
    MFMA_MODE(4, c40, c41);                                                     \
    __builtin_amdgcn_s_setprio(0);                                              \
  } while (0)

  // ---- prologue: fill slots 0,1 (stages 0,1); scf prep overlaps DMA
  ISSUE_SLOT(0u);
  ISSUE_SLOT(36864u);
  if (tid < 256) {
    int b = row0 + tid;
    float s = se[b];
    float l0 = fmaf(s, gw[0], gb[0]);
    float l1 = fmaf(s, gw[1], gb[1]);
    float l2 = fmaf(s, gw[2], gb[2]);
    float l3 = fmaf(s, gw[3], gb[3]);
    float mx = fmaxf(fmaxf(l0, l1), fmaxf(l2, l3));
    float e0 = __expf(l0 - mx), e1 = __expf(l1 - mx);
    float e2 = __expf(l2 - mx), e3 = __expf(l3 - mx);
    float mix = 1.0f / (1.0f + __expf(-curv[b]));
    float inv = mix / (e0 + e1 + e2 + e3);
    scf[0 * 256 + tid] = e0 * inv;
    scf[1 * 256 + tid] = e1 * inv;
    scf[2 * 256 + tid] = e2 * inv;
    scf[3 * 256 + tid] = e3 * inv;
    scf[4 * 256 + tid] = 1.0f - mix;
  }
  WAITL;                               // stage 0 landed (own wave); stage 1 in flight
  __builtin_amdgcn_s_barrier();        // all waves: stage 0 ready
  __builtin_amdgcn_sched_barrier(0);
  READ_PH0(0u);

  // ---- main loop: stages 0..29 (uniform body), tail 30,31
  unsigned int cS = 0u, nS = 36864u, iS = 73728u;
#pragma unroll 1
  for (int s = 0; s < 30; ++s) {
    ISSUE_SLOT(iS);                    // stage s+2 into the freed slot
    PH1_READS(cS);                     // modes 2-4 frags of stage s
    MFMA_ALL5;                         // ph0 carried + ph1 (counted lgkmcnt)
    WAITL;                             // stage s+1 landed (own wave); s+2 in flight
    __builtin_amdgcn_s_barrier();      // all waves: stage s+1 ready
    __builtin_amdgcn_sched_barrier(0);
    READ_PH0(nS);                      // ph0 frags of stage s+1
    unsigned int t_ = cS; cS = nS; nS = iS; iS = t_;
  }
  // tail: stage 30 (no issue; drain for stage 31), stage 31
  {
    PH1_READS(cS);
    MFMA_ALL5;
    asm volatile("s_waitcnt vmcnt(0)" ::: "memory");  // stage 31 landed
    __builtin_amdgcn_s_barrier();
    __builtin_amdgcn_sched_barrier(0);
    READ_PH0(nS);
  }
  {
    PH1_READS(nS);
    MFMA_ALL5;
  }

  // ---- epilogue: mode-combine -> LDS repack (fp32, pitch 68) -> float4 stores
  __syncthreads();
  float* fbuf = (float*)smem;  // 256 x 68 fp32 = 69632 B (scf at 110592 safe)
#pragma unroll
  for (int ti = 0; ti < 4; ++ti) {
    int rl = wrow + ti * 16 + q * 4;
#pragma unroll
    for (int tj = 0; tj < 2; ++tj) {
      int cc = wcol + tj * 16 + ln;
#pragma unroll
      for (int r = 0; r < 4; ++r) {
        float v = 0.f;
#pragma unroll
        for (int m = 0; m < 5; ++m)
          v += scf[m * 256 + rl + r] * acc[m][ti][tj][r];
        fbuf[(rl + r) * 68 + cc] = v;
      }
    }
  }
  __syncthreads();
#pragma unroll
  for (int i = 0; i < 8; ++i) {
    int L = i * 512 + tid;          // 4096 float4s = 256 rows x 16
    int row = L >> 4, c4 = L & 15;
    float4v v = *(const float4v*)(fbuf + row * 68 + c4 * 4);
    float cb = scf[4 * 256 + row];
    float4v pb = *(const float4v*)(prjb + col0 + c4 * 4);
    v += cb * pb;
    *(float4v*)(out + (size_t)(row0 + row) * O_DIM + col0 + c4 * 4) = v;
  }
#undef ISSUE_SLOT
#undef WAITL
#undef READ_PH0
#undef MFMA_MODE
#undef PH1_READS
#undef MFMA_ALL5
}

// ---------------------------------------------------------------------------
extern "C" void kernel_launch(void* const* d_in, const int* in_sizes, int n_in,
                              void* d_out, int out_size, void* d_ws, size_t ws_size,
                              hipStream_t stream) {
  const float* state = (const float*)d_in[0];
  const float* se    = (const float*)d_in[1];
  const float* curv  = (const float*)d_in[2];
  const float* basis = (const float*)d_in[3];
  const float* gw    = (const float*)d_in[4];
  const float* gb    = (const float*)d_in[5];
  const float* prjw  = (const float*)d_in[6];
  const float* prjb  = (const float*)d_in[7];
  float* out = (float*)d_out;

  char* ws = (char*)d_ws;
  unsigned short* Abf = (unsigned short*)ws;                               // 16 MB
  unsigned short* Wt  = (unsigned short*)(ws + (size_t)16 * 1024 * 1024);  // 10 MB

  prep_inputs<<<5376, 256, 0, stream>>>(state, basis, prjw, Abf, Wt);
  dim3 gg(B_DIM / 256, O_DIM / 64);
  gemm_fused<<<gg, 512, 0, stream>>>(Abf, Wt, se, curv, gw, gb, prjb, out);
}